// Round 2
// baseline (1078.325 us; speedup 1.0000x reference)
//
#include <hip/hip_runtime.h>
#include <hip/hip_bf16.h>

// Problem constants
#define BB 32
#define QQ 300
#define DD 256
#define HH 8
#define DHH 32
#define LL 4
#define PP 4
#define SS 8500

// ---------------------------------------------------------------------------
// Generic tiled GEMM: C[M x BN] = A[M x 256] @ W[256 x BN] + bias[BN]
// Block: 256 threads, BM=64 rows per block, full BN columns (BN = 128 or 256).
// Register blocking: 8 rows x (BN/32) cols per thread.
// M must be a multiple of 64 (true for all call sites: 272000, 9600).
// ---------------------------------------------------------------------------
__device__ inline void store_val(float* p, float v) { *p = v; }
__device__ inline void store_val(__hip_bfloat16* p, float v) { *p = __float2bfloat16(v); }

template <int BN, typename OUT_T>
__global__ __launch_bounds__(256) void gemm_rowtile(
    const float* __restrict__ A, const float* __restrict__ W,
    const float* __restrict__ bias, OUT_T* __restrict__ C) {
  constexpr int K = 256, BK = 32, BM = 64;
  constexpr int NJ = BN / 32;
  __shared__ float As[BM][BK + 1];
  __shared__ float Bs[BK][BN];

  const int t = threadIdx.x;
  const int row0 = blockIdx.x * BM;
  const int tm = t >> 5;   // 0..7
  const int tn = t & 31;   // 0..31

  float acc[8][NJ];
#pragma unroll
  for (int i = 0; i < 8; ++i)
#pragma unroll
    for (int j = 0; j < NJ; ++j) acc[i][j] = 0.f;

  for (int k0 = 0; k0 < K; k0 += BK) {
    // Stage A tile: 64 x 32 = 2048 floats, 8 per thread, coalesced in k.
#pragma unroll
    for (int i = 0; i < (BM * BK) / 256; ++i) {
      int idx = t + i * 256;
      int r = idx / BK, kk = idx % BK;
      As[r][kk] = A[(size_t)(row0 + r) * K + (k0 + kk)];
    }
    // Stage W tile: 32 x BN floats, coalesced in n.
#pragma unroll
    for (int i = 0; i < (BK * BN) / 256; ++i) {
      int idx = t + i * 256;
      int kk = idx / BN, n = idx % BN;
      Bs[kk][n] = W[(size_t)(k0 + kk) * BN + n];
    }
    __syncthreads();

#pragma unroll
    for (int kk = 0; kk < BK; ++kk) {
      float a[8], bb[NJ];
#pragma unroll
      for (int i = 0; i < 8; ++i) a[i] = As[tm * 8 + i][kk];
#pragma unroll
      for (int j = 0; j < NJ; ++j) bb[j] = Bs[kk][tn + j * 32];
#pragma unroll
      for (int i = 0; i < 8; ++i)
#pragma unroll
        for (int j = 0; j < NJ; ++j) acc[i][j] += a[i] * bb[j];
    }
    __syncthreads();
  }

#pragma unroll
  for (int i = 0; i < 8; ++i) {
    const size_t row = (size_t)row0 + tm * 8 + i;
#pragma unroll
    for (int j = 0; j < NJ; ++j) {
      const int col = tn + j * 32;
      store_val(&C[row * BN + col], acc[i][j] + bias[col]);
    }
  }
}

// ---------------------------------------------------------------------------
// Softmax over groups of 16 (in place). One thread per (b,q,h).
// ---------------------------------------------------------------------------
__global__ __launch_bounds__(256) void softmax16(float* __restrict__ aw, int n) {
  int i = blockIdx.x * blockDim.x + threadIdx.x;
  if (i >= n) return;
  float* p = aw + (size_t)i * 16;
  float m = p[0];
#pragma unroll
  for (int j = 1; j < 16; ++j) m = fmaxf(m, p[j]);
  float e[16];
  float s = 0.f;
#pragma unroll
  for (int j = 0; j < 16; ++j) { e[j] = __expf(p[j] - m); s += e[j]; }
  float inv = 1.f / s;
#pragma unroll
  for (int j = 0; j < 16; ++j) p[j] = e[j] * inv;
}

// ---------------------------------------------------------------------------
// Bilinear sampling + attention-weighted sum.
// Block = (b,q); thread t: h = t>>5, dh = t&31.
// value: bf16, (B, S, H*DH) row-major (channel contiguous).
// ---------------------------------------------------------------------------
__device__ inline float tap(const __hip_bfloat16* __restrict__ vb, int st,
                            int x, int y, int ww, int hh) {
  if (x < 0 || x >= ww || y < 0 || y >= hh) return 0.f;
  return __bfloat162float(vb[(size_t)(st + y * ww + x) * DD]);
}

__global__ __launch_bounds__(256) void sample_kernel(
    const __hip_bfloat16* __restrict__ value, const float* __restrict__ off,
    const float* __restrict__ aw, const float* __restrict__ refpts,
    float* __restrict__ sampled) {
  __shared__ float s_off[256];
  __shared__ float s_aw[128];
  __shared__ float s_ref[4];

  const int bq = blockIdx.x;       // b*Q + q
  const int b = bq / QQ;
  const int t = threadIdx.x;

  s_off[t] = off[(size_t)bq * 256 + t];
  if (t < 128) s_aw[t] = aw[(size_t)bq * 128 + t];
  if (t < 4) s_ref[t] = refpts[(size_t)bq * 4 + t];
  __syncthreads();

  const int h = t >> 5, dh = t & 31;
  const float rx = s_ref[0], ry = s_ref[1], rw = s_ref[2], rh = s_ref[3];

  const int dim_arr[4] = {80, 40, 20, 10};
  const int st_arr[4] = {0, 6400, 8000, 8400};

  const __hip_bfloat16* vbase = value + (size_t)b * SS * DD + h * DHH + dh;

  float acc = 0.f;
#pragma unroll
  for (int l = 0; l < LL; ++l) {
    const int dim = dim_arr[l];
    const int st = st_arr[l];
    const float fdim = (float)dim;
#pragma unroll
    for (int p = 0; p < PP; ++p) {
      const int oi = (h * 16 + l * 4 + p) * 2;
      const float locx = rx + s_off[oi] * rw * 0.125f;
      const float locy = ry + s_off[oi + 1] * rh * 0.125f;
      // grid->pixel (align_corners=False): x = ((gx+1)*W - 1)/2 with gx=2*loc-1
      const float x = locx * fdim - 0.5f;
      const float y = locy * fdim - 0.5f;
      const float x0f = floorf(x), y0f = floorf(y);
      const float fx = x - x0f, fy = y - y0f;
      const int x0 = (int)x0f, y0 = (int)y0f;
      const int x1 = x0 + 1, y1 = y0 + 1;
      const float v00 = tap(vbase, st, x0, y0, dim, dim);
      const float v01 = tap(vbase, st, x1, y0, dim, dim);
      const float v10 = tap(vbase, st, x0, y1, dim, dim);
      const float v11 = tap(vbase, st, x1, y1, dim, dim);
      const float sv = v00 * (1.f - fx) * (1.f - fy) + v01 * fx * (1.f - fy) +
                       v10 * (1.f - fx) * fy + v11 * fx * fy;
      acc += sv * s_aw[h * 16 + l * 4 + p];
    }
  }
  sampled[(size_t)bq * 256 + t] = acc;
}

// ---------------------------------------------------------------------------
// Launch
// ---------------------------------------------------------------------------
extern "C" void kernel_launch(void* const* d_in, const int* in_sizes, int n_in,
                              void* d_out, int out_size, void* d_ws, size_t ws_size,
                              hipStream_t stream) {
  const float* hidden = (const float*)d_in[0];   // (B, Q, 256)
  const float* ehs    = (const float*)d_in[1];   // (B, S, 256)
  const float* refpts = (const float*)d_in[2];   // (B, Q, 1, 4)
  const float* W_val  = (const float*)d_in[3];
  const float* b_val  = (const float*)d_in[4];
  const float* W_off  = (const float*)d_in[5];
  const float* b_off  = (const float*)d_in[6];
  const float* W_attn = (const float*)d_in[7];
  const float* b_attn = (const float*)d_in[8];
  const float* W_out  = (const float*)d_in[9];
  const float* b_out  = (const float*)d_in[10];
  float* out = (float*)d_out;

  // Workspace layout
  char* ws = (char*)d_ws;
  __hip_bfloat16* value = (__hip_bfloat16*)ws;                 // B*S*256 bf16 = 139,264,000 B
  float* offb = (float*)(ws + 139264000);                      // B*Q*256 f32 = 9,830,400 B
  float* awb  = (float*)(ws + 139264000 + 9830400);            // B*Q*128 f32 = 4,915,200 B
  float* samp = (float*)(ws + 139264000 + 9830400 + 4915200);  // B*Q*256 f32 = 9,830,400 B

  const int M_val = BB * SS;   // 272000 (multiple of 64)
  const int M_q   = BB * QQ;   // 9600   (multiple of 64)

  // 1. value = ehs @ W_val + b_val  (store bf16)
  gemm_rowtile<256, __hip_bfloat16><<<M_val / 64, 256, 0, stream>>>(ehs, W_val, b_val, value);
  // 2. off = hidden @ W_off + b_off
  gemm_rowtile<256, float><<<M_q / 64, 256, 0, stream>>>(hidden, W_off, b_off, offb);
  // 3. aw_raw = hidden @ W_attn + b_attn
  gemm_rowtile<128, float><<<M_q / 64, 256, 0, stream>>>(hidden, W_attn, b_attn, awb);
  // 4. softmax over L*P=16 per (b,q,h)
  softmax16<<<(M_q * HH + 255) / 256, 256, 0, stream>>>(awb, M_q * HH);
  // 5. bilinear sampling + weighted sum
  sample_kernel<<<M_q, 256, 0, stream>>>(value, offb, awb, refpts, samp);
  // 6. out = samp @ W_out + b_out
  gemm_rowtile<256, float><<<M_q / 64, 256, 0, stream>>>(samp, W_out, b_out, out);
}

// Round 3
// 529.036 us; speedup vs baseline: 2.0383x; 2.0383x over previous
//
#include <hip/hip_runtime.h>
#include <hip/hip_bf16.h>

// Problem constants
#define BB 32
#define QQ 300
#define DD 256
#define HH 8
#define DHH 32
#define LL 4
#define PP 4
#define SS 8500

typedef __attribute__((ext_vector_type(8))) short bf16x8;
typedef __attribute__((ext_vector_type(4))) float f32x4;

__device__ inline unsigned short f2bf(float f) {
  unsigned int u = __builtin_bit_cast(unsigned int, f);
  unsigned int r = (u + 0x7FFFu + ((u >> 16) & 1u)) >> 16;
  return (unsigned short)r;
}

// ---------------------------------------------------------------------------
// Convert W_val (256x256 f32, [k][n]) -> bf16 transposed [n][k].
// ---------------------------------------------------------------------------
__global__ __launch_bounds__(256) void wcvt_kernel(const float* __restrict__ W,
                                                   unsigned short* __restrict__ wbfT) {
  int t = blockIdx.x * 256 + threadIdx.x;   // 0..65535
  int k = t >> 8, n = t & 255;              // coalesced read of W[k][*]
  wbfT[(size_t)n * 256 + k] = f2bf(W[(size_t)k * 256 + n]);
}

// ---------------------------------------------------------------------------
// Value GEMM via MFMA: C[M x 256] = bf16(A[M x 256] f32) @ bf16(W) + bias.
// 512 threads = 8 waves (2 x 4). BM=128, BN=256, BK=64.
// Wave tile 64x64 = 4x4 fragments of 16x16 (acc 64 VGPRs).
// A staged fp32->bf16 into LDS; W pre-converted/transposed [n][k].
// ---------------------------------------------------------------------------
__global__ __launch_bounds__(512, 1) void gemm_val_mfma(
    const float* __restrict__ A, const unsigned short* __restrict__ WbfT,
    const float* __restrict__ bias, __hip_bfloat16* __restrict__ C) {
  __shared__ unsigned short Alds[128][72];   // pad 8 -> stride 144 B (16B-aligned, 2-way banks)
  __shared__ unsigned short Blds[256][72];

  const int t = threadIdx.x;
  const int lane = t & 63;
  const int wid = t >> 6;
  const int wm = wid >> 2;   // 0..1
  const int wn = wid & 3;    // 0..3
  const int row0 = blockIdx.x * 128;

  f32x4 acc[4][4];
#pragma unroll
  for (int m = 0; m < 4; ++m)
#pragma unroll
    for (int n = 0; n < 4; ++n) acc[m][n] = {0.f, 0.f, 0.f, 0.f};

  for (int k0 = 0; k0 < 256; k0 += 64) {
    // Stage A: 128 rows x 64 f32 -> bf16. 512 thr x 4 x (16B load + cvt + 8B ds_write)
#pragma unroll
    for (int i = 0; i < 4; ++i) {
      int unit = i * 512 + t;          // 16-byte-load units, 16 per row
      int r = unit >> 4;
      int kk = (unit & 15) * 4;
      float4 v = *reinterpret_cast<const float4*>(A + (size_t)(row0 + r) * 256 + k0 + kk);
      ushort4 h;
      h.x = f2bf(v.x); h.y = f2bf(v.y); h.z = f2bf(v.z); h.w = f2bf(v.w);
      *reinterpret_cast<ushort4*>(&Alds[r][kk]) = h;
    }
    // Stage B: 256 cols x 64 bf16 (already bf16, [n][k] layout -> contiguous)
#pragma unroll
    for (int i = 0; i < 4; ++i) {
      int unit = i * 512 + t;          // 16-byte units, 8 per row
      int c = unit >> 3;
      int kk = (unit & 7) * 8;
      uint4 v = *reinterpret_cast<const uint4*>(WbfT + (size_t)c * 256 + k0 + kk);
      *reinterpret_cast<uint4*>(&Blds[c][kk]) = v;
    }
    __syncthreads();

#pragma unroll
    for (int ks = 0; ks < 2; ++ks) {
      bf16x8 am[4], bn[4];
#pragma unroll
      for (int m = 0; m < 4; ++m)
        am[m] = *reinterpret_cast<const bf16x8*>(
            &Alds[wm * 64 + m * 16 + (lane & 15)][ks * 32 + (lane >> 4) * 8]);
#pragma unroll
      for (int n = 0; n < 4; ++n)
        bn[n] = *reinterpret_cast<const bf16x8*>(
            &Blds[wn * 64 + n * 16 + (lane & 15)][ks * 32 + (lane >> 4) * 8]);
#pragma unroll
      for (int m = 0; m < 4; ++m)
#pragma unroll
        for (int n = 0; n < 4; ++n)
          acc[m][n] = __builtin_amdgcn_mfma_f32_16x16x32_bf16(am[m], bn[n], acc[m][n], 0, 0, 0);
    }
    __syncthreads();
  }

  // Epilogue: C/D layout col=lane&15, row=(lane>>4)*4+j (m89-verified)
  const int cr = lane >> 4;
  const int cc = lane & 15;
#pragma unroll
  for (int n = 0; n < 4; ++n) {
    const int col = wn * 64 + n * 16 + cc;
    const float bv = bias[col];
#pragma unroll
    for (int m = 0; m < 4; ++m) {
      const int rbase = row0 + wm * 64 + m * 16 + cr * 4;
#pragma unroll
      for (int j = 0; j < 4; ++j)
        C[(size_t)(rbase + j) * 256 + col] = __float2bfloat16(acc[m][n][j] + bv);
    }
  }
}

// ---------------------------------------------------------------------------
// fp32 tiled GEMM for the small projections (kept from round 1).
// ---------------------------------------------------------------------------
__device__ inline void store_val(float* p, float v) { *p = v; }
__device__ inline void store_val(__hip_bfloat16* p, float v) { *p = __float2bfloat16(v); }

template <int BN, typename OUT_T>
__global__ __launch_bounds__(256) void gemm_rowtile(
    const float* __restrict__ A, const float* __restrict__ W,
    const float* __restrict__ bias, OUT_T* __restrict__ C) {
  constexpr int K = 256, BK = 32, BM = 64;
  constexpr int NJ = BN / 32;
  __shared__ float As[BM][BK + 1];
  __shared__ float Bs[BK][BN];

  const int t = threadIdx.x;
  const int row0 = blockIdx.x * BM;
  const int tm = t >> 5;
  const int tn = t & 31;

  float acc[8][NJ];
#pragma unroll
  for (int i = 0; i < 8; ++i)
#pragma unroll
    for (int j = 0; j < NJ; ++j) acc[i][j] = 0.f;

  for (int k0 = 0; k0 < K; k0 += BK) {
#pragma unroll
    for (int i = 0; i < (BM * BK) / 256; ++i) {
      int idx = t + i * 256;
      int r = idx / BK, kk = idx % BK;
      As[r][kk] = A[(size_t)(row0 + r) * K + (k0 + kk)];
    }
#pragma unroll
    for (int i = 0; i < (BK * BN) / 256; ++i) {
      int idx = t + i * 256;
      int kk = idx / BN, n = idx % BN;
      Bs[kk][n] = W[(size_t)(k0 + kk) * BN + n];
    }
    __syncthreads();

#pragma unroll
    for (int kk = 0; kk < BK; ++kk) {
      float a[8], bb[NJ];
#pragma unroll
      for (int i = 0; i < 8; ++i) a[i] = As[tm * 8 + i][kk];
#pragma unroll
      for (int j = 0; j < NJ; ++j) bb[j] = Bs[kk][tn + j * 32];
#pragma unroll
      for (int i = 0; i < 8; ++i)
#pragma unroll
        for (int j = 0; j < NJ; ++j) acc[i][j] += a[i] * bb[j];
    }
    __syncthreads();
  }

#pragma unroll
  for (int i = 0; i < 8; ++i) {
    const size_t row = (size_t)row0 + tm * 8 + i;
#pragma unroll
    for (int j = 0; j < NJ; ++j) {
      const int col = tn + j * 32;
      store_val(&C[row * BN + col], acc[i][j] + bias[col]);
    }
  }
}

// ---------------------------------------------------------------------------
// Softmax over groups of 16 (in place). One thread per (b,q,h).
// ---------------------------------------------------------------------------
__global__ __launch_bounds__(256) void softmax16(float* __restrict__ aw, int n) {
  int i = blockIdx.x * blockDim.x + threadIdx.x;
  if (i >= n) return;
  float* p = aw + (size_t)i * 16;
  float m = p[0];
#pragma unroll
  for (int j = 1; j < 16; ++j) m = fmaxf(m, p[j]);
  float e[16];
  float s = 0.f;
#pragma unroll
  for (int j = 0; j < 16; ++j) { e[j] = __expf(p[j] - m); s += e[j]; }
  float inv = 1.f / s;
#pragma unroll
  for (int j = 0; j < 16; ++j) p[j] = e[j] * inv;
}

// ---------------------------------------------------------------------------
// Bilinear sampling + attention-weighted sum. Block=(b,q), thread=(h,dh).
// ---------------------------------------------------------------------------
__device__ inline float tap(const __hip_bfloat16* __restrict__ vb, int st,
                            int x, int y, int ww, int hh) {
  if (x < 0 || x >= ww || y < 0 || y >= hh) return 0.f;
  return __bfloat162float(vb[(size_t)(st + y * ww + x) * DD]);
}

__global__ __launch_bounds__(256) void sample_kernel(
    const __hip_bfloat16* __restrict__ value, const float* __restrict__ off,
    const float* __restrict__ aw, const float* __restrict__ refpts,
    float* __restrict__ sampled) {
  __shared__ float s_off[256];
  __shared__ float s_aw[128];
  __shared__ float s_ref[4];

  const int bq = blockIdx.x;
  const int b = bq / QQ;
  const int t = threadIdx.x;

  s_off[t] = off[(size_t)bq * 256 + t];
  if (t < 128) s_aw[t] = aw[(size_t)bq * 128 + t];
  if (t < 4) s_ref[t] = refpts[(size_t)bq * 4 + t];
  __syncthreads();

  const int h = t >> 5, dh = t & 31;
  const float rx = s_ref[0], ry = s_ref[1], rw = s_ref[2], rh = s_ref[3];

  const int dim_arr[4] = {80, 40, 20, 10};
  const int st_arr[4] = {0, 6400, 8000, 8400};

  const __hip_bfloat16* vbase = value + (size_t)b * SS * DD + h * DHH + dh;

  float acc = 0.f;
#pragma unroll
  for (int l = 0; l < LL; ++l) {
    const int dim = dim_arr[l];
    const int st = st_arr[l];
    const float fdim = (float)dim;
#pragma unroll
    for (int p = 0; p < PP; ++p) {
      const int oi = (h * 16 + l * 4 + p) * 2;
      const float locx = rx + s_off[oi] * rw * 0.125f;
      const float locy = ry + s_off[oi + 1] * rh * 0.125f;
      const float x = locx * fdim - 0.5f;
      const float y = locy * fdim - 0.5f;
      const float x0f = floorf(x), y0f = floorf(y);
      const float fx = x - x0f, fy = y - y0f;
      const int x0 = (int)x0f, y0 = (int)y0f;
      const int x1 = x0 + 1, y1 = y0 + 1;
      const float v00 = tap(vbase, st, x0, y0, dim, dim);
      const float v01 = tap(vbase, st, x1, y0, dim, dim);
      const float v10 = tap(vbase, st, x0, y1, dim, dim);
      const float v11 = tap(vbase, st, x1, y1, dim, dim);
      const float sv = v00 * (1.f - fx) * (1.f - fy) + v01 * fx * (1.f - fy) +
                       v10 * (1.f - fx) * fy + v11 * fx * fy;
      acc += sv * s_aw[h * 16 + l * 4 + p];
    }
  }
  sampled[(size_t)bq * 256 + t] = acc;
}

// ---------------------------------------------------------------------------
// Launch
// ---------------------------------------------------------------------------
extern "C" void kernel_launch(void* const* d_in, const int* in_sizes, int n_in,
                              void* d_out, int out_size, void* d_ws, size_t ws_size,
                              hipStream_t stream) {
  const float* hidden = (const float*)d_in[0];
  const float* ehs    = (const float*)d_in[1];
  const float* refpts = (const float*)d_in[2];
  const float* W_val  = (const float*)d_in[3];
  const float* b_val  = (const float*)d_in[4];
  const float* W_off  = (const float*)d_in[5];
  const float* b_off  = (const float*)d_in[6];
  const float* W_attn = (const float*)d_in[7];
  const float* b_attn = (const float*)d_in[8];
  const float* W_out  = (const float*)d_in[9];
  const float* b_out  = (const float*)d_in[10];
  float* out = (float*)d_out;

  // Workspace layout
  char* ws = (char*)d_ws;
  __hip_bfloat16* value = (__hip_bfloat16*)ws;                 // 139,264,000 B
  float* offb = (float*)(ws + 139264000);                      // 9,830,400 B
  float* awb  = (float*)(ws + 139264000 + 9830400);            // 4,915,200 B
  float* samp = (float*)(ws + 139264000 + 9830400 + 4915200);  // 9,830,400 B
  unsigned short* wbfT = (unsigned short*)(ws + 139264000 + 9830400 + 4915200 + 9830400); // 131,072 B

  const int M_val = BB * SS;   // 272000
  const int M_q   = BB * QQ;   // 9600

  // 0. W_val -> bf16 transposed
  wcvt_kernel<<<256, 256, 0, stream>>>(W_val, wbfT);
  // 1. value = ehs @ W_val + b_val  (bf16, MFMA)
  gemm_val_mfma<<<M_val / 128, 512, 0, stream>>>(ehs, wbfT, b_val, value);
  // 2. off = hidden @ W_off + b_off  (fp32 — feeds sample positions)
  gemm_rowtile<256, float><<<M_q / 64, 256, 0, stream>>>(hidden, W_off, b_off, offb);
  // 3. aw_raw = hidden @ W_attn + b_attn
  gemm_rowtile<128, float><<<M_q / 64, 256, 0, stream>>>(hidden, W_attn, b_attn, awb);
  // 4. softmax over L*P=16
  softmax16<<<(M_q * HH + 255) / 256, 256, 0, stream>>>(awb, M_q * HH);
  // 5. bilinear sampling + weighted sum
  sample_kernel<<<M_q, 256, 0, stream>>>(value, offb, awb, refpts, samp);
  // 6. out = samp @ W_out + b_out
  gemm_rowtile<256, float><<<M_q / 64, 256, 0, stream>>>(samp, W_out, b_out, out);
}

// Round 4
// 286.300 us; speedup vs baseline: 3.7664x; 1.8478x over previous
//
#include <hip/hip_runtime.h>
#include <hip/hip_bf16.h>

// Problem constants
#define BB 32
#define QQ 300
#define DD 256
#define HH 8
#define DHH 32
#define LL 4
#define PP 4
#define SS 8500

typedef __attribute__((ext_vector_type(8))) short bf16x8;
typedef __attribute__((ext_vector_type(4))) float f32x4;

__device__ inline unsigned short f2bf(float f) {
  unsigned int u = __builtin_bit_cast(unsigned int, f);
  unsigned int r = (u + 0x7FFFu + ((u >> 16) & 1u)) >> 16;
  return (unsigned short)r;
}

// ---------------------------------------------------------------------------
// Convert W_val (256x256 f32, [k][n]) -> bf16 transposed [n][k].
// ---------------------------------------------------------------------------
__global__ __launch_bounds__(256) void wcvt_kernel(const float* __restrict__ W,
                                                   unsigned short* __restrict__ wbfT) {
  int t = blockIdx.x * 256 + threadIdx.x;   // 0..65535
  int k = t >> 8, n = t & 255;              // coalesced read of W[k][*]
  wbfT[(size_t)n * 256 + k] = f2bf(W[(size_t)k * 256 + n]);
}

// ---------------------------------------------------------------------------
// Value GEMM via MFMA: C[M x 256] = bf16(A[M x 256] f32) @ bf16(W) + bias.
// 512 threads = 8 waves (2 x 4). BM=128, BN=256, BK=64.
// ---------------------------------------------------------------------------
__global__ __launch_bounds__(512, 1) void gemm_val_mfma(
    const float* __restrict__ A, const unsigned short* __restrict__ WbfT,
    const float* __restrict__ bias, __hip_bfloat16* __restrict__ C) {
  __shared__ unsigned short Alds[128][72];
  __shared__ unsigned short Blds[256][72];

  const int t = threadIdx.x;
  const int lane = t & 63;
  const int wid = t >> 6;
  const int wm = wid >> 2;   // 0..1
  const int wn = wid & 3;    // 0..3
  const int row0 = blockIdx.x * 128;

  f32x4 acc[4][4];
#pragma unroll
  for (int m = 0; m < 4; ++m)
#pragma unroll
    for (int n = 0; n < 4; ++n) acc[m][n] = {0.f, 0.f, 0.f, 0.f};

  for (int k0 = 0; k0 < 256; k0 += 64) {
#pragma unroll
    for (int i = 0; i < 4; ++i) {
      int unit = i * 512 + t;
      int r = unit >> 4;
      int kk = (unit & 15) * 4;
      float4 v = *reinterpret_cast<const float4*>(A + (size_t)(row0 + r) * 256 + k0 + kk);
      ushort4 h;
      h.x = f2bf(v.x); h.y = f2bf(v.y); h.z = f2bf(v.z); h.w = f2bf(v.w);
      *reinterpret_cast<ushort4*>(&Alds[r][kk]) = h;
    }
#pragma unroll
    for (int i = 0; i < 4; ++i) {
      int unit = i * 512 + t;
      int c = unit >> 3;
      int kk = (unit & 7) * 8;
      uint4 v = *reinterpret_cast<const uint4*>(WbfT + (size_t)c * 256 + k0 + kk);
      *reinterpret_cast<uint4*>(&Blds[c][kk]) = v;
    }
    __syncthreads();

#pragma unroll
    for (int ks = 0; ks < 2; ++ks) {
      bf16x8 am[4], bn[4];
#pragma unroll
      for (int m = 0; m < 4; ++m)
        am[m] = *reinterpret_cast<const bf16x8*>(
            &Alds[wm * 64 + m * 16 + (lane & 15)][ks * 32 + (lane >> 4) * 8]);
#pragma unroll
      for (int n = 0; n < 4; ++n)
        bn[n] = *reinterpret_cast<const bf16x8*>(
            &Blds[wn * 64 + n * 16 + (lane & 15)][ks * 32 + (lane >> 4) * 8]);
#pragma unroll
      for (int m = 0; m < 4; ++m)
#pragma unroll
        for (int n = 0; n < 4; ++n)
          acc[m][n] = __builtin_amdgcn_mfma_f32_16x16x32_bf16(am[m], bn[n], acc[m][n], 0, 0, 0);
    }
    __syncthreads();
  }

  const int cr = lane >> 4;
  const int cc = lane & 15;
#pragma unroll
  for (int n = 0; n < 4; ++n) {
    const int col = wn * 64 + n * 16 + cc;
    const float bv = bias[col];
#pragma unroll
    for (int m = 0; m < 4; ++m) {
      const int rbase = row0 + wm * 64 + m * 16 + cr * 4;
#pragma unroll
      for (int j = 0; j < 4; ++j)
        C[(size_t)(rbase + j) * 256 + col] = __float2bfloat16(acc[m][n][j] + bv);
    }
  }
}

// ---------------------------------------------------------------------------
// fp32 tiled GEMM for the small projections.
// ---------------------------------------------------------------------------
__device__ inline void store_val(float* p, float v) { *p = v; }
__device__ inline void store_val(__hip_bfloat16* p, float v) { *p = __float2bfloat16(v); }

template <int BN, typename OUT_T>
__global__ __launch_bounds__(256) void gemm_rowtile(
    const float* __restrict__ A, const float* __restrict__ W,
    const float* __restrict__ bias, OUT_T* __restrict__ C) {
  constexpr int K = 256, BK = 32, BM = 64;
  constexpr int NJ = BN / 32;
  __shared__ float As[BM][BK + 1];
  __shared__ float Bs[BK][BN];

  const int t = threadIdx.x;
  const int row0 = blockIdx.x * BM;
  const int tm = t >> 5;
  const int tn = t & 31;

  float acc[8][NJ];
#pragma unroll
  for (int i = 0; i < 8; ++i)
#pragma unroll
    for (int j = 0; j < NJ; ++j) acc[i][j] = 0.f;

  for (int k0 = 0; k0 < K; k0 += BK) {
#pragma unroll
    for (int i = 0; i < (BM * BK) / 256; ++i) {
      int idx = t + i * 256;
      int r = idx / BK, kk = idx % BK;
      As[r][kk] = A[(size_t)(row0 + r) * K + (k0 + kk)];
    }
#pragma unroll
    for (int i = 0; i < (BK * BN) / 256; ++i) {
      int idx = t + i * 256;
      int kk = idx / BN, n = idx % BN;
      Bs[kk][n] = W[(size_t)(k0 + kk) * BN + n];
    }
    __syncthreads();

#pragma unroll
    for (int kk = 0; kk < BK; ++kk) {
      float a[8], bb[NJ];
#pragma unroll
      for (int i = 0; i < 8; ++i) a[i] = As[tm * 8 + i][kk];
#pragma unroll
      for (int j = 0; j < NJ; ++j) bb[j] = Bs[kk][tn + j * 32];
#pragma unroll
      for (int i = 0; i < 8; ++i)
#pragma unroll
        for (int j = 0; j < NJ; ++j) acc[i][j] += a[i] * bb[j];
    }
    __syncthreads();
  }

#pragma unroll
  for (int i = 0; i < 8; ++i) {
    const size_t row = (size_t)row0 + tm * 8 + i;
#pragma unroll
    for (int j = 0; j < NJ; ++j) {
      const int col = tn + j * 32;
      store_val(&C[row * BN + col], acc[i][j] + bias[col]);
    }
  }
}

// ---------------------------------------------------------------------------
// Bilinear sampling + fused softmax + weighted sum.
// 32 threads per query: h = 0..7, c4 = 0..3 (8 channels each, uint4 taps).
// Block = 256 threads = 8 queries. Branchless taps (clamp + predicated weight).
// ---------------------------------------------------------------------------
#define QPB 8

__global__ __launch_bounds__(256) void sample_kernel(
    const __hip_bfloat16* __restrict__ value, const float* __restrict__ off,
    const float* __restrict__ logits, const float* __restrict__ refpts,
    float* __restrict__ sampled) {
  __shared__ float s_off[QPB][256];
  __shared__ float s_lg[QPB][128];
  __shared__ float s_ref[QPB][4];

  // XCD-chunked bijective swizzle: grid = 1200 = 8 * 150.
  const int nb = gridDim.x;
  const int bswz = (blockIdx.x % 8) * (nb / 8) + blockIdx.x / 8;
  const int bq0 = bswz * QPB;
  const int t = threadIdx.x;

  for (int i = t; i < QPB * 256; i += 256) s_off[i >> 8][i & 255] = off[(size_t)bq0 * 256 + i];
  for (int i = t; i < QPB * 128; i += 256) s_lg[i >> 7][i & 127] = logits[(size_t)bq0 * 128 + i];
  if (t < QPB * 4) s_ref[t >> 2][t & 3] = refpts[(size_t)bq0 * 4 + t];
  __syncthreads();

  const int qi = t >> 5;        // query in block
  const int sub = t & 31;
  const int h = sub >> 2;       // head
  const int c4 = sub & 3;       // channel group (8 ch)
  const int bq = bq0 + qi;
  const int b = bq / QQ;

  // Softmax over 16 (redundant across the 4 c4 threads; reads broadcast)
  float w[16];
  {
    const float* lg = &s_lg[qi][h * 16];
    float m = lg[0];
#pragma unroll
    for (int j = 1; j < 16; ++j) m = fmaxf(m, lg[j]);
    float s = 0.f;
#pragma unroll
    for (int j = 0; j < 16; ++j) { w[j] = __expf(lg[j] - m); s += w[j]; }
    float inv = 1.f / s;
#pragma unroll
    for (int j = 0; j < 16; ++j) w[j] *= inv;
  }

  const float rx = s_ref[qi][0], ry = s_ref[qi][1];
  const float rw = s_ref[qi][2], rh = s_ref[qi][3];
  const unsigned short* vb =
      (const unsigned short*)value + (size_t)b * SS * DD + h * DHH + c4 * 8;

  float acc[8];
#pragma unroll
  for (int j = 0; j < 8; ++j) acc[j] = 0.f;

  const int dims[4] = {80, 40, 20, 10};
  const int sts[4] = {0, 6400, 8000, 8400};

#pragma unroll
  for (int l = 0; l < LL; ++l) {
    const int dim = dims[l];
    const int st = sts[l];
    const float fdim = (float)dim;
#pragma unroll
    for (int p = 0; p < PP; ++p) {
      const int tapi = l * 4 + p;
      const int oi = (h * 16 + tapi) * 2;
      const float locx = rx + s_off[qi][oi] * rw * 0.125f;
      const float locy = ry + s_off[qi][oi + 1] * rh * 0.125f;
      const float x = locx * fdim - 0.5f;
      const float y = locy * fdim - 0.5f;
      const float x0f = floorf(x), y0f = floorf(y);
      const float fx = x - x0f, fy = y - y0f;
      const int x0 = (int)x0f, y0 = (int)y0f;
      const float wt = w[tapi];
      const float bw[4] = {(1.f - fx) * (1.f - fy), fx * (1.f - fy),
                           (1.f - fx) * fy, fx * fy};
      const int cx[4] = {x0, x0 + 1, x0, x0 + 1};
      const int cy[4] = {y0, y0, y0 + 1, y0 + 1};
#pragma unroll
      for (int c = 0; c < 4; ++c) {
        const int xi = cx[c], yi = cy[c];
        const bool valid = (xi >= 0) & (xi < dim) & (yi >= 0) & (yi < dim);
        const int xc = min(max(xi, 0), dim - 1);
        const int yc = min(max(yi, 0), dim - 1);
        const uint4 v = *reinterpret_cast<const uint4*>(
            vb + (size_t)(st + yc * dim + xc) * DD);
        const float wv = valid ? bw[c] * wt : 0.f;
        const unsigned u[4] = {v.x, v.y, v.z, v.w};
#pragma unroll
        for (int k = 0; k < 4; ++k) {
          const float lo = __builtin_bit_cast(float, u[k] << 16);
          const float hi = __builtin_bit_cast(float, u[k] & 0xFFFF0000u);
          acc[2 * k] += lo * wv;
          acc[2 * k + 1] += hi * wv;
        }
      }
    }
  }

  float* outp = &sampled[(size_t)bq * 256 + h * DHH + c4 * 8];
  *reinterpret_cast<float4*>(outp) = make_float4(acc[0], acc[1], acc[2], acc[3]);
  *reinterpret_cast<float4*>(outp + 4) = make_float4(acc[4], acc[5], acc[6], acc[7]);
}

// ---------------------------------------------------------------------------
// Launch
// ---------------------------------------------------------------------------
extern "C" void kernel_launch(void* const* d_in, const int* in_sizes, int n_in,
                              void* d_out, int out_size, void* d_ws, size_t ws_size,
                              hipStream_t stream) {
  const float* hidden = (const float*)d_in[0];
  const float* ehs    = (const float*)d_in[1];
  const float* refpts = (const float*)d_in[2];
  const float* W_val  = (const float*)d_in[3];
  const float* b_val  = (const float*)d_in[4];
  const float* W_off  = (const float*)d_in[5];
  const float* b_off  = (const float*)d_in[6];
  const float* W_attn = (const float*)d_in[7];
  const float* b_attn = (const float*)d_in[8];
  const float* W_out  = (const float*)d_in[9];
  const float* b_out  = (const float*)d_in[10];
  float* out = (float*)d_out;

  // Workspace layout
  char* ws = (char*)d_ws;
  __hip_bfloat16* value = (__hip_bfloat16*)ws;                 // 139,264,000 B
  float* offb = (float*)(ws + 139264000);                      // 9,830,400 B
  float* awb  = (float*)(ws + 139264000 + 9830400);            // 4,915,200 B
  float* samp = (float*)(ws + 139264000 + 9830400 + 4915200);  // 9,830,400 B
  unsigned short* wbfT = (unsigned short*)(ws + 139264000 + 9830400 + 4915200 + 9830400);

  const int M_val = BB * SS;   // 272000
  const int M_q   = BB * QQ;   // 9600

  // 0. W_val -> bf16 transposed
  wcvt_kernel<<<256, 256, 0, stream>>>(W_val, wbfT);
  // 1. value = ehs @ W_val + b_val  (bf16, MFMA)
  gemm_val_mfma<<<M_val / 128, 512, 0, stream>>>(ehs, wbfT, b_val, value);
  // 2. off = hidden @ W_off + b_off  (fp32 — feeds sample positions)
  gemm_rowtile<256, float><<<M_q / 64, 256, 0, stream>>>(hidden, W_off, b_off, offb);
  // 3. aw logits = hidden @ W_attn + b_attn (softmax fused into sampling)
  gemm_rowtile<128, float><<<M_q / 64, 256, 0, stream>>>(hidden, W_attn, b_attn, awb);
  // 4. bilinear sampling + fused softmax + weighted sum
  sample_kernel<<<M_q / QPB, 256, 0, stream>>>(value, offb, awb, refpts, samp);
  // 5. out = samp @ W_out + b_out
  gemm_rowtile<256, float><<<M_q / 64, 256, 0, stream>>>(samp, W_out, b_out, out);
}